// Round 15
// baseline (181.801 us; speedup 1.0000x reference)
//
#include <hip/hip_runtime.h>

#define N_TOK  1024
#define C_DIM  384
#define H_NUM  12
#define D_PAIR 128
#define PD_DIM 144
#define NOP_DIM 1472
#define KD     96        // folded QK depth (3 k-steps of 32)
#define NPROJ  368       // 23 o-blocks x 16 n-blocks
#define NWOUT  36        // 6x6 WoutT transpose tiles
#define NBIAS  2048      // persistent stream blocks (4 waves x 8 units x 16 rows each)
#define SCALE_F 0.17677669529663687f

typedef __attribute__((ext_vector_type(8))) short    short8;
typedef __attribute__((ext_vector_type(8))) _Float16 half8;
typedef __attribute__((ext_vector_type(4))) float    f32x4;
typedef __attribute__((ext_vector_type(4))) unsigned u32x4;
typedef __attribute__((ext_vector_type(4))) unsigned short ushort4v;
typedef __attribute__((ext_vector_type(2))) _Float16 half2v;
typedef _Float16 f16;

#if defined(__has_builtin)
#if __has_builtin(__builtin_amdgcn_fdot2)
#define HAVE_FDOT2 1
#endif
#if __has_builtin(__builtin_amdgcn_perm)
#define HAVE_PERM 1
#endif
#if __has_builtin(__builtin_amdgcn_global_load_lds)
#define HAVE_GLL 1
#endif
#endif

static __device__ __forceinline__ float fdot2f(half2v a, half2v b, float c) {
#ifdef HAVE_FDOT2
  return __builtin_amdgcn_fdot2(a, b, c, false);
#else
  return c + (float)a.x * (float)b.x + (float)a.y * (float)b.y;
#endif
}

// pack two f32 -> bf16x2 (truncation) in one v_perm
static __device__ __forceinline__ unsigned packbf(float a, float b) {
#ifdef HAVE_PERM
  return __builtin_amdgcn_perm(__builtin_bit_cast(unsigned, b),
                               __builtin_bit_cast(unsigned, a), 0x07060302u);
#else
  return (__builtin_bit_cast(unsigned, a) >> 16) |
         (__builtin_bit_cast(unsigned, b) & 0xffff0000u);
#endif
}

static __device__ __forceinline__ unsigned short f2bf(float f) {
  unsigned u = __builtin_bit_cast(unsigned, f);
  u = u + 0x7fffu + ((u >> 16) & 1u);
  return (unsigned short)(u >> 16);
}
static __device__ __forceinline__ float bf2f(unsigned short h) {
  return __builtin_bit_cast(float, (unsigned)h << 16);
}
static __device__ __forceinline__ unsigned short f16bits(float x) {
  return __builtin_bit_cast(unsigned short, (f16)x);
}
static __device__ __forceinline__ float f16f(unsigned short b) {
  return (float)__builtin_bit_cast(f16, b);
}
static __device__ __forceinline__ float f16hi(float x) { return (float)(f16)x; }

// ============ k_projbias: proj GEMM + WoutT transpose + persistent pair-bias stream ============
#define LDT 40
__global__ __launch_bounds__(256, 2) void k_projbias(
    const float* __restrict__ single, const float* __restrict__ Wq,
    const float* __restrict__ Wk, const float* __restrict__ Wv,
    const float* __restrict__ Wpq, const float* __restrict__ Wpk,
    const float* __restrict__ Wpair, const float* __restrict__ Wout,
    float* __restrict__ proj, const float* __restrict__ pair,
    f16* __restrict__ WoutT, f16* __restrict__ bias) {
  __shared__ __align__(16) unsigned char SMEM[65536];
  const int t = threadIdx.x, lane = t & 63;
  if (blockIdx.x < NPROJ) {
    // ---------- proj: split-bf16 3-pass MFMA GEMM, inputs read f32 + converted inline ----------
    unsigned short* Ah = (unsigned short*)SMEM;
    unsigned short* Al = Ah + 64 * LDT;
    unsigned short* Bh = Al + 64 * LDT;
    unsigned short* Bl = Bh + 64 * LDT;
    const int wid = t >> 6;
    const int wr = wid >> 1, wc = wid & 1;
    const int n0 = (blockIdx.x / 23) * 64, o0 = (blockIdx.x % 23) * 64;
    f32x4 acc[2][2] = {};
    const int srow = t >> 2, skk = (t & 3) * 8;   // A-staging map (64n x 32k)
    const int kr = t >> 3, og = t & 7;            // B-staging map (32k x 8 o-groups)
    const int ob = o0 + og * 8;
    const float* bsrc;
    int bstride, bloc;
    if      (ob < 384)  { bsrc = Wq;  bstride = C_DIM;  bloc = ob; }
    else if (ob < 768)  { bsrc = Wk;  bstride = C_DIM;  bloc = ob - 384; }
    else if (ob < 1152) { bsrc = Wv;  bstride = C_DIM;  bloc = ob - 768; }
    else if (ob < 1296) { bsrc = Wpq; bstride = PD_DIM; bloc = ob - 1152; }
    else if (ob < 1440) { bsrc = Wpk; bstride = PD_DIM; bloc = ob - 1296; }
    else                { bsrc = nullptr; bstride = 0;  bloc = 0; }
    for (int k0 = 0; k0 < C_DIM; k0 += 32) {
      {
        const float* ap = single + (size_t)(n0 + srow) * C_DIM + k0 + skk;
        f32x4 a0 = *(const f32x4*)ap;
        f32x4 a1 = *(const f32x4*)(ap + 4);
        float xs[8] = {a0.x, a0.y, a0.z, a0.w, a1.x, a1.y, a1.z, a1.w};
        short8 hi, lo;
#pragma unroll
        for (int j = 0; j < 8; ++j) {
          unsigned short h = f2bf(xs[j]);
          hi[j] = (short)h;
          lo[j] = (short)f2bf(xs[j] - bf2f(h));
        }
        *(short8*)&Ah[srow * LDT + skk] = hi;
        *(short8*)&Al[srow * LDT + skk] = lo;
      }
      {
        float xs[8] = {0.f, 0.f, 0.f, 0.f, 0.f, 0.f, 0.f, 0.f};
        if (bsrc) {
          const float* bp = bsrc + (size_t)(k0 + kr) * bstride + bloc;
          f32x4 b0 = *(const f32x4*)bp;
          f32x4 b1 = *(const f32x4*)(bp + 4);
          xs[0] = b0.x; xs[1] = b0.y; xs[2] = b0.z; xs[3] = b0.w;
          xs[4] = b1.x; xs[5] = b1.y; xs[6] = b1.z; xs[7] = b1.w;
        }
#pragma unroll
        for (int j = 0; j < 8; ++j) {
          unsigned short h = f2bf(xs[j]);
          Bh[(og * 8 + j) * LDT + kr] = h;
          Bl[(og * 8 + j) * LDT + kr] = f2bf(xs[j] - bf2f(h));
        }
      }
      __syncthreads();
#pragma unroll
      for (int i = 0; i < 2; ++i) {
        const int ar = (wr * 32 + i * 16 + (lane & 15)) * LDT + (lane >> 4) * 8;
        short8 ah = *(short8*)&Ah[ar];
        short8 al = *(short8*)&Al[ar];
#pragma unroll
        for (int j = 0; j < 2; ++j) {
          const int br = (wc * 32 + j * 16 + (lane & 15)) * LDT + (lane >> 4) * 8;
          short8 bh = *(short8*)&Bh[br];
          short8 bl = *(short8*)&Bl[br];
          acc[i][j] = __builtin_amdgcn_mfma_f32_16x16x32_bf16(ah, bh, acc[i][j], 0, 0, 0);
          acc[i][j] = __builtin_amdgcn_mfma_f32_16x16x32_bf16(ah, bl, acc[i][j], 0, 0, 0);
          acc[i][j] = __builtin_amdgcn_mfma_f32_16x16x32_bf16(al, bh, acc[i][j], 0, 0, 0);
        }
      }
      __syncthreads();
    }
#pragma unroll
    for (int i = 0; i < 2; ++i)
#pragma unroll
      for (int j = 0; j < 2; ++j)
#pragma unroll
        for (int rr = 0; rr < 4; ++rr) {
          int r = n0 + wr * 32 + i * 16 + (lane >> 4) * 4 + rr;
          int c = o0 + wc * 32 + j * 16 + (lane & 15);
          proj[(size_t)r * NOP_DIM + c] = acc[i][j][rr];
        }
  } else if (blockIdx.x < NPROJ + NWOUT) {
    // ---------- WoutT transpose ----------
    float* T = (float*)SMEM;  // [64][68] padded
    const int b2 = blockIdx.x - NPROJ;
    const int k0 = (b2 % 6) * 64, o0 = (b2 / 6) * 64;
    const int r = t >> 2, cq = t & 3;
    {
      const float* srcrow = Wout + (size_t)(k0 + r) * C_DIM + o0 + cq * 16;
#pragma unroll
      for (int j = 0; j < 4; ++j) {
        f32x4 v = *(const f32x4*)(srcrow + j * 4);
        T[r * 68 + cq * 16 + j * 4 + 0] = v.x;
        T[r * 68 + cq * 16 + j * 4 + 1] = v.y;
        T[r * 68 + cq * 16 + j * 4 + 2] = v.z;
        T[r * 68 + cq * 16 + j * 4 + 3] = v.w;
      }
    }
    __syncthreads();
    {
      ushort4v w0, w1, w2, w3;
#pragma unroll
      for (int j = 0; j < 4; ++j) {
        w0[j] = f16bits(T[(cq * 16 + j) * 68 + r]);
        w1[j] = f16bits(T[(cq * 16 + 4 + j) * 68 + r]);
        w2[j] = f16bits(T[(cq * 16 + 8 + j) * 68 + r]);
        w3[j] = f16bits(T[(cq * 16 + 12 + j) * 68 + r]);
      }
      f16* dst = WoutT + (size_t)(o0 + r) * C_DIM + k0 + cq * 16;
      *(ushort4v*)(dst + 0)  = w0;
      *(ushort4v*)(dst + 4)  = w1;
      *(ushort4v*)(dst + 8)  = w2;
      *(ushort4v*)(dst + 12) = w3;
    }
  } else {
    // ---------- bias: persistent wave-private dbuf stream, counted vmcnt, NO barriers ----------
    const int w = t >> 6;
    const int r16 = lane & 15, g = lane >> 4;
    short8 bfr[4];
#pragma unroll
    for (int kst = 0; kst < 4; ++kst)
#pragma unroll
      for (int j = 0; j < 8; ++j) {
        int k = kst * 32 + g * 8 + j;
        float v = (r16 < 12) ? Wpair[k * H_NUM + r16] : 0.f;
        bfr[kst][j] = (short)f2bf(v);
      }
    const int wgi = ((int)blockIdx.x - NPROJ - NWOUT) * 4 + w;  // 0..8191
    const size_t base_nm = (size_t)wgi * 128;                   // 8 units x 16 rows
    unsigned char* WBUF = SMEM + w * 16384;                     // 2 x 8KB per wave
    const char* gunit0 = (const char*)(pair + base_nm * D_PAIR);
    const unsigned xr = (unsigned)((r16 & 7) << 4);

    auto issue = [&](int u, int b) {
      const char* gb = gunit0 + (size_t)u * 8192;
#pragma unroll
      for (int i = 0; i < 8; ++i) {
        unsigned B = (unsigned)(i * 1024 + lane * 16);   // linear LDS byte in unit
        unsigned src = B ^ (((B >> 9) & 7u) << 4);       // sigma-permuted global byte
#ifdef HAVE_GLL
        __builtin_amdgcn_global_load_lds(
            (const __attribute__((address_space(1))) unsigned*)(gb + src),
            (__attribute__((address_space(3))) unsigned*)(WBUF + b * 8192 + i * 1024),
            16, 0, 0);
#else
        *(f32x4*)(WBUF + b * 8192 + B) = *(const f32x4*)(gb + src);
#endif
      }
    };
    issue(0, 0);
    issue(1, 1);
#pragma unroll
    for (int u = 0; u < 8; ++u) {
#ifdef HAVE_GLL
      if (u == 7) { asm volatile("s_waitcnt vmcnt(1)" ::: "memory"); }
      else        { asm volatile("s_waitcnt vmcnt(8)" ::: "memory"); }
      __builtin_amdgcn_sched_barrier(0);
#endif
      const unsigned char* CB = WBUF + (u & 1) * 8192;
      f32x4 acc = {};
#pragma unroll
      for (int kst = 0; kst < 4; ++kst) {
        unsigned L = (unsigned)(r16 * 512 + kst * 128 + g * 32);
        f32x4 v0 = *(const f32x4*)(CB + (L ^ xr));
        f32x4 v1 = *(const f32x4*)(CB + ((L + 16) ^ xr));
        u32x4 pk;
        pk.x = packbf(v0.x, v0.y);
        pk.y = packbf(v0.z, v0.w);
        pk.z = packbf(v1.x, v1.y);
        pk.w = packbf(v1.z, v1.w);
        acc = __builtin_amdgcn_mfma_f32_16x16x32_bf16(__builtin_bit_cast(short8, pk),
                                                      bfr[kst], acc, 0, 0, 0);
      }
      if (r16 < 12) {
        ushort4v pkk;
#pragma unroll
        for (int rr = 0; rr < 4; ++rr) pkk[rr] = f16bits(acc[rr]);
        *(ushort4v*)(bias + (((size_t)r16 << 20) + base_nm + u * 16 + g * 4)) = pkk;
      }
      if (u < 6) {
#ifdef HAVE_GLL
        // ensure our LDS reads of this buffer retired before refilling it
        asm volatile("s_waitcnt lgkmcnt(0)" ::: "memory");
        __builtin_amdgcn_sched_barrier(0);
#endif
        issue(u + 2, u & 1);
      }
    }
  }
}

// ============ k_assemble ============
__global__ __launch_bounds__(256) void k_assemble(
    const float* __restrict__ proj, const float* __restrict__ rot,
    const float* __restrict__ bq, const float* __restrict__ bk,
    const float* __restrict__ bv, const float* __restrict__ bpq,
    const float* __restrict__ bpk,
    f16* __restrict__ Qtf, f16* __restrict__ Ktf, f16* __restrict__ Vt) {
  const int n0 = blockIdx.x * 4, t = threadIdx.x;
  __shared__ float qv[4][384], kv[4][384], qgv[4][144], kgv[4][144], skv[4][12];
  __shared__ f16 vbuf[384][4];
#pragma unroll
  for (int ln = 0; ln < 4; ++ln) {
    const float* pr = proj + (size_t)(n0 + ln) * NOP_DIM;
    const float* R = rot + (n0 + ln) * 9;
    for (int c = t; c < 384; c += 256) {
      qv[ln][c] = pr[c] + bq[c];
      kv[ln][c] = pr[384 + c] + bk[c];
      vbuf[c][ln] = (f16)(pr[768 + c] + bv[c]);
    }
    for (int s = t; s < 144; s += 256) {
      int h = s / 12, pj = s - h * 12, p = pj / 3, j = pj - p * 3;
      float qg = 0.f, kg = 0.f;
      for (int i = 0; i < 3; ++i) {
        qg += (pr[1152 + h * 12 + p * 3 + i] + bpq[h * 12 + p * 3 + i]) * R[i * 3 + j];
        kg += (pr[1296 + h * 12 + p * 3 + i] + bpk[h * 12 + p * 3 + i]) * R[i * 3 + j];
      }
      qgv[ln][s] = qg;
      kgv[ln][s] = kg;
    }
  }
  __syncthreads();
  if (t < 48) {
    int ln = t / 12, h = t - ln * 12;
    float sk = 0.f;
    for (int pj = 0; pj < 12; ++pj) sk += kgv[ln][h * 12 + pj] * kgv[ln][h * 12 + pj];
    skv[ln][h] = -0.5f * SCALE_F * sk;
  }
  __syncthreads();
  for (int idx = t; idx < 4 * 12 * KD; idx += 256) {
    int ln = idx / 1152, rem = idx - ln * 1152;
    int h = rem / KD, s = rem - h * KD;
    float qo = 0.f, ko = 0.f;
    if (s < 32) {
      qo = SCALE_F * qv[ln][h * 32 + s];
      ko = kv[ln][h * 32 + s];
    } else if (s < 44) {
      int j = s - 32;
      qo = f16hi(SCALE_F * qgv[ln][h * 12 + j]);
      ko = f16hi(kgv[ln][h * 12 + j]);
    } else if (s < 56) {
      int j = s - 44;
      qo = f16hi(SCALE_F * qgv[ln][h * 12 + j]);
      ko = kgv[ln][h * 12 + j] - f16hi(kgv[ln][h * 12 + j]);
    } else if (s < 68) {
      int j = s - 56;
      float sq = SCALE_F * qgv[ln][h * 12 + j];
      qo = sq - f16hi(sq);
      ko = f16hi(kgv[ln][h * 12 + j]);
    } else if (s == 68) {
      qo = 1.f;
      ko = f16hi(skv[ln][h]);
    } else if (s == 69) {
      qo = 1.f;
      ko = skv[ln][h] - f16hi(skv[ln][h]);
    }
    Qtf[((size_t)h * N_TOK + n0 + ln) * KD + s] = (f16)qo;
    Ktf[((size_t)h * N_TOK + n0 + ln) * KD + s] = (f16)ko;
  }
  __syncthreads();
  for (int r = t; r < 384; r += 256)
    *(ushort4v*)(Vt + ((size_t)r << 10) + n0) = *(ushort4v*)&vbuf[r][0];
}

// ============ k_attn2: flash attention; Kt/Vt direct-from-L2, bias dbuf LDS ============
__global__ __launch_bounds__(256, 4) void k_attn2(const f16* __restrict__ Qtf,
                                                  const f16* __restrict__ Ktf,
                                                  const f16* __restrict__ Vt,
                                                  const f16* __restrict__ bias,
                                                  float* __restrict__ psum) {
  __shared__ unsigned short biasS[2][64 * 72];
  __shared__ unsigned short PS[4][16 * 72];
  const int h = blockIdx.x, nt = blockIdx.y, ms = blockIdx.z;
  const int t = threadIdx.x, lane = t & 63, w = t >> 6;
  const int r16 = lane & 15, g = lane >> 4;
  const int n0 = nt * 64, mbase = ms * 256;

  half8 qf[3];
  {
    const f16* Qrow = Qtf + ((size_t)h * N_TOK + n0 + w * 16 + r16) * KD;
#pragma unroll
    for (int kst = 0; kst < 3; ++kst)
      qf[kst] = __builtin_bit_cast(half8, *(const u32x4*)(Qrow + kst * 32 + g * 8));
  }
  f32x4 accv[2] = {};
  float Mh[4] = {-3e38f, -3e38f, -3e38f, -3e38f};
  float Sh[4] = {0.f, 0.f, 0.f, 0.f};

  {
    const int rb = t >> 2;
    const f16* src = bias + ((size_t)h << 20) + (size_t)(n0 + rb) * N_TOK + mbase + (t & 3) * 16;
#pragma unroll
    for (int i = 0; i < 2; ++i)
      *(u32x4*)&biasS[0][rb * 72 + (t & 3) * 16 + i * 8] = *(const u32x4*)(src + i * 8);
  }
  __syncthreads();

  for (int sc = 0; sc < 4; ++sc) {
    const int m0 = mbase + sc * 64;
    const int cur = sc & 1;
    if (sc < 3) {
      const int rb = t >> 2;
      const f16* src = bias + ((size_t)h << 20) + (size_t)(n0 + rb) * N_TOK + (m0 + 64) + (t & 3) * 16;
#pragma unroll
      for (int i = 0; i < 2; ++i)
        *(u32x4*)&biasS[cur ^ 1][rb * 72 + (t & 3) * 16 + i * 8] = *(const u32x4*)(src + i * 8);
    }

    f32x4 sacc[4] = {};
#pragma unroll
    for (int mt = 0; mt < 4; ++mt) {
      const f16* Krow = Ktf + ((size_t)h * N_TOK + m0 + mt * 16 + r16) * KD;
#pragma unroll
      for (int kst = 0; kst < 3; ++kst) {
        half8 b = __builtin_bit_cast(half8, *(const u32x4*)(Krow + kst * 32 + g * 8));
        sacc[mt] = __builtin_amdgcn_mfma_f32_16x16x32_f16(qf[kst], b, sacc[mt], 0, 0, 0);
      }
    }
#pragma unroll
    for (int mt = 0; mt < 4; ++mt)
#pragma unroll
      for (int rr = 0; rr < 4; ++rr)
        sacc[mt][rr] += f16f(biasS[cur][(w * 16 + g * 4 + rr) * 72 + mt * 16 + r16]);

    float e[4], Mn[4];
#pragma unroll
    for (int rr = 0; rr < 4; ++rr) {
      float mx = fmaxf(fmaxf(sacc[0][rr], sacc[1][rr]), fmaxf(sacc[2][rr], sacc[3][rr]));
#pragma unroll
      for (int msk = 1; msk < 16; msk <<= 1) mx = fmaxf(mx, __shfl_xor(mx, msk));
      Mn[rr] = fmaxf(Mh[rr], mx);
      e[rr] = __expf(Mh[rr] - Mn[rr]);
      Mh[rr] = Mn[rr];
    }
    float rs[4] = {0.f, 0.f, 0.f, 0.f};
#pragma unroll
    for (int mt = 0; mt < 4; ++mt)
#pragma unroll
      for (int rr = 0; rr < 4; ++rr) {
        float p = __expf(sacc[mt][rr] - Mn[rr]);
        rs[rr] += p;
        PS[w][(g * 4 + rr) * 72 + mt * 16 + r16] = f16bits(p);
      }
#pragma unroll
    for (int rr = 0; rr < 4; ++rr) {
#pragma unroll
      for (int msk = 1; msk < 16; msk <<= 1) rs[rr] += __shfl_xor(rs[rr], msk);
      Sh[rr] = Sh[rr] * e[rr] + rs[rr];
    }
#pragma unroll
    for (int vt = 0; vt < 2; ++vt)
#pragma unroll
      for (int rr = 0; rr < 4; ++rr) accv[vt][rr] *= e[rr];

#pragma unroll
    for (int kst2 = 0; kst2 < 2; ++kst2) {
      half8 pa = __builtin_bit_cast(half8, *(u32x4*)&PS[w][r16 * 72 + kst2 * 32 + g * 8]);
#pragma unroll
      for (int vt = 0; vt < 2; ++vt) {
        half8 bvv = __builtin_bit_cast(
            half8, *(const u32x4*)(Vt + (((size_t)(h * 32 + vt * 16 + r16)) << 10) + m0 + kst2 * 32 + g * 8));
        accv[vt] = __builtin_amdgcn_mfma_f32_16x16x32_f16(pa, bvv, accv[vt], 0, 0, 0);
      }
    }
    __syncthreads();
  }

  float* ps = psum + (((size_t)h * 4 + ms) * N_TOK) * 36;
#pragma unroll
  for (int rr = 0; rr < 4; ++rr) {
    int n = n0 + w * 16 + g * 4 + rr;
    if (r16 == 0) {
      ps[(size_t)n * 36 + 0] = Mh[rr];
      ps[(size_t)n * 36 + 1] = Sh[rr];
    }
#pragma unroll
    for (int vt = 0; vt < 2; ++vt)
      ps[(size_t)n * 36 + 2 + vt * 16 + r16] = accv[vt][rr];
  }
}

// ============ k_epi: 4 tokens/block; merge + outproj + residual + LayerNorm ============
__global__ __launch_bounds__(384) void k_epi(const float* __restrict__ psum,
                                             const f16* __restrict__ WoutT,
                                             const float* __restrict__ bout,
                                             const float* __restrict__ single,
                                             const float* __restrict__ gamma,
                                             const float* __restrict__ beta,
                                             float* __restrict__ out) {
  const int nb = blockIdx.x * 4, t = threadIdx.x;
  __shared__ f16 ar4[4][384];
  __shared__ float red[4][6][2];
  const int h = t >> 5, vc = t & 31, w = t >> 6;
  const size_t sstr = (size_t)N_TOK * 36;
#pragma unroll
  for (int tk = 0; tk < 4; ++tk) {
    const float* pb = psum + ((size_t)(h * 4) * N_TOK + (nb + tk)) * 36;
    float M = -3e38f;
#pragma unroll
    for (int s = 0; s < 4; ++s) M = fmaxf(M, pb[s * sstr]);
    float den = 0.f, num = 0.f;
#pragma unroll
    for (int s = 0; s < 4; ++s) {
      float e = __expf(pb[s * sstr] - M);
      den += pb[s * sstr + 1] * e;
      num += pb[s * sstr + 2 + vc] * e;
    }
    ar4[tk][t] = (f16)(num / den);
  }
  __syncthreads();
  float d[4] = {0.f, 0.f, 0.f, 0.f};
  {
    const u32x4* wp = (const u32x4*)(WoutT + (size_t)t * C_DIM);
    for (int i = 0; i < 48; ++i) {
      u32x4 wv = wp[i];
      half2v w0 = __builtin_bit_cast(half2v, wv.x);
      half2v w1 = __builtin_bit_cast(half2v, wv.y);
      half2v w2 = __builtin_bit_cast(half2v, wv.z);
      half2v w3 = __builtin_bit_cast(half2v, wv.w);
#pragma unroll
      for (int tk = 0; tk < 4; ++tk) {
        u32x4 av = *(const u32x4*)&ar4[tk][i * 8];
        d[tk] = fdot2f(__builtin_bit_cast(half2v, av.x), w0, d[tk]);
        d[tk] = fdot2f(__builtin_bit_cast(half2v, av.y), w1, d[tk]);
        d[tk] = fdot2f(__builtin_bit_cast(half2v, av.z), w2, d[tk]);
        d[tk] = fdot2f(__builtin_bit_cast(half2v, av.w), w3, d[tk]);
      }
    }
  }
  const float bo_ = bout[t], ga = gamma[t], be = beta[t];
  float x[4];
#pragma unroll
  for (int tk = 0; tk < 4; ++tk) {
    x[tk] = d[tk] + bo_ + single[(size_t)(nb + tk) * C_DIM + t];
    float s1 = x[tk], q1 = x[tk] * x[tk];
#pragma unroll
    for (int m = 1; m < 64; m <<= 1) {
      s1 += __shfl_xor(s1, m);
      q1 += __shfl_xor(q1, m);
    }
    if ((t & 63) == 0) { red[tk][w][0] = s1; red[tk][w][1] = q1; }
  }
  __syncthreads();
#pragma unroll
  for (int tk = 0; tk < 4; ++tk) {
    float S = 0.f, Q = 0.f;
#pragma unroll
    for (int i = 0; i < 6; ++i) { S += red[tk][i][0]; Q += red[tk][i][1]; }
    const float mu = S * (1.f / 384.f);
    const float var = Q * (1.f / 384.f) - mu * mu;
    const float rs = rsqrtf(var + 1e-5f);
    out[(size_t)(nb + tk) * C_DIM + t] = (x[tk] - mu) * rs * ga + be;
  }
}

// ============ launcher ============
extern "C" void kernel_launch(void* const* d_in, const int* in_sizes, int n_in,
                              void* d_out, int out_size, void* d_ws, size_t ws_size,
                              hipStream_t stream) {
  const float* single = (const float*)d_in[0];
  const float* pair   = (const float*)d_in[1];
  const float* rot    = (const float*)d_in[2];
  const float* Wq = (const float*)d_in[4];   const float* bq = (const float*)d_in[5];
  const float* Wk = (const float*)d_in[6];   const float* bk = (const float*)d_in[7];
  const float* Wv = (const float*)d_in[8];   const float* bv = (const float*)d_in[9];
  const float* Wpair = (const float*)d_in[10];
  const float* Wpq = (const float*)d_in[12]; const float* bpq = (const float*)d_in[13];
  const float* Wpk = (const float*)d_in[14]; const float* bpk = (const float*)d_in[15];
  const float* Wout = (const float*)d_in[16]; const float* bout = (const float*)d_in[17];
  const float* gamma = (const float*)d_in[18]; const float* beta = (const float*)d_in[19];
  float* out = (float*)d_out;

  char* ws = (char*)d_ws;
  size_t off = 0;
  auto alloc = [&](size_t bytes) -> void* {
    void* p = ws + off;
    off += (bytes + 255) & ~(size_t)255;
    return p;
  };
  f16* Qtf = (f16*)alloc((size_t)12 * N_TOK * KD * 2);
  f16* Ktf = (f16*)alloc((size_t)12 * N_TOK * KD * 2);
  f16* Vt  = (f16*)alloc((size_t)C_DIM * N_TOK * 2);
  f16* WoutT = (f16*)alloc((size_t)C_DIM * C_DIM * 2);
  float* proj = (float*)alloc((size_t)N_TOK * NOP_DIM * 4);
  f16* bias = (f16*)alloc((size_t)12 * N_TOK * N_TOK * 2);
  float* psum = (float*)alloc((size_t)12 * 4 * N_TOK * 36 * 4);

  k_projbias<<<dim3(NPROJ + NWOUT + NBIAS), dim3(256), 0, stream>>>(
      single, Wq, Wk, Wv, Wpq, Wpk, Wpair, Wout, proj, pair, WoutT, bias);
  k_assemble<<<dim3(N_TOK / 4), dim3(256), 0, stream>>>(proj, rot, bq, bk, bv, bpq, bpk, Qtf, Ktf, Vt);
  k_attn2<<<dim3(12, 16, 4), dim3(256), 0, stream>>>(Qtf, Ktf, Vt, bias, psum);
  k_epi<<<dim3(N_TOK / 4), dim3(384), 0, stream>>>(psum, WoutT, bout, single, gamma, beta, out);
}

// Round 16
// 170.000 us; speedup vs baseline: 1.0694x; 1.0694x over previous
//
#include <hip/hip_runtime.h>

#define N_TOK  1024
#define C_DIM  384
#define H_NUM  12
#define D_PAIR 128
#define PD_DIM 144
#define NOP_DIM 1472
#define KD     96        // folded QK depth (3 k-steps of 32)
#define NPROJ  368       // 23 o-blocks x 16 n-blocks
#define NWOUT  36        // 6x6 WoutT transpose tiles
#define SCALE_F 0.17677669529663687f

typedef __attribute__((ext_vector_type(8))) short    short8;
typedef __attribute__((ext_vector_type(8))) _Float16 half8;
typedef __attribute__((ext_vector_type(4))) float    f32x4;
typedef __attribute__((ext_vector_type(4))) unsigned u32x4;
typedef __attribute__((ext_vector_type(4))) unsigned short ushort4v;
typedef __attribute__((ext_vector_type(2))) _Float16 half2v;
typedef _Float16 f16;

#if defined(__has_builtin)
#if __has_builtin(__builtin_amdgcn_fdot2)
#define HAVE_FDOT2 1
#endif
#if __has_builtin(__builtin_amdgcn_perm)
#define HAVE_PERM 1
#endif
#if __has_builtin(__builtin_amdgcn_global_load_lds)
#define HAVE_GLL 1
#endif
#endif

static __device__ __forceinline__ float fdot2f(half2v a, half2v b, float c) {
#ifdef HAVE_FDOT2
  return __builtin_amdgcn_fdot2(a, b, c, false);
#else
  return c + (float)a.x * (float)b.x + (float)a.y * (float)b.y;
#endif
}

// pack two f32 -> bf16x2 (truncation) in one v_perm
static __device__ __forceinline__ unsigned packbf(float a, float b) {
#ifdef HAVE_PERM
  return __builtin_amdgcn_perm(__builtin_bit_cast(unsigned, b),
                               __builtin_bit_cast(unsigned, a), 0x07060302u);
#else
  return (__builtin_bit_cast(unsigned, a) >> 16) |
         (__builtin_bit_cast(unsigned, b) & 0xffff0000u);
#endif
}

static __device__ __forceinline__ unsigned short f2bf(float f) {
  unsigned u = __builtin_bit_cast(unsigned, f);
  u = u + 0x7fffu + ((u >> 16) & 1u);
  return (unsigned short)(u >> 16);
}
static __device__ __forceinline__ float bf2f(unsigned short h) {
  return __builtin_bit_cast(float, (unsigned)h << 16);
}
static __device__ __forceinline__ unsigned short f16bits(float x) {
  return __builtin_bit_cast(unsigned short, (f16)x);
}
static __device__ __forceinline__ float f16f(unsigned short b) {
  return (float)__builtin_bit_cast(f16, b);
}
static __device__ __forceinline__ float f16hi(float x) { return (float)(f16)x; }

// ============ k_projbias: proj GEMM (inline f32->split-bf16) + WoutT transpose + pair-bias stream ============
#define LDT 40
__global__ __launch_bounds__(256, 4) void k_projbias(
    const float* __restrict__ single, const float* __restrict__ Wq,
    const float* __restrict__ Wk, const float* __restrict__ Wv,
    const float* __restrict__ Wpq, const float* __restrict__ Wpk,
    const float* __restrict__ Wpair, const float* __restrict__ Wout,
    float* __restrict__ proj, const float* __restrict__ pair,
    f16* __restrict__ WoutT, f16* __restrict__ bias) {
  __shared__ __align__(16) unsigned char SMEM[32768];
  const int t = threadIdx.x, lane = t & 63;
  if (blockIdx.x < NPROJ) {
    // ---------- proj: split-bf16 3-pass MFMA GEMM, inputs read f32 + converted inline ----------
    unsigned short* Ah = (unsigned short*)SMEM;
    unsigned short* Al = Ah + 64 * LDT;
    unsigned short* Bh = Al + 64 * LDT;
    unsigned short* Bl = Bh + 64 * LDT;
    const int wid = t >> 6;
    const int wr = wid >> 1, wc = wid & 1;
    const int n0 = (blockIdx.x / 23) * 64, o0 = (blockIdx.x % 23) * 64;
    f32x4 acc[2][2] = {};
    const int srow = t >> 2, skk = (t & 3) * 8;   // A-staging map (64n x 32k)
    const int kr = t >> 3, og = t & 7;            // B-staging map (32k x 8 o-groups)
    const int ob = o0 + og * 8;
    const float* bsrc;
    int bstride, bloc;
    if      (ob < 384)  { bsrc = Wq;  bstride = C_DIM;  bloc = ob; }
    else if (ob < 768)  { bsrc = Wk;  bstride = C_DIM;  bloc = ob - 384; }
    else if (ob < 1152) { bsrc = Wv;  bstride = C_DIM;  bloc = ob - 768; }
    else if (ob < 1296) { bsrc = Wpq; bstride = PD_DIM; bloc = ob - 1152; }
    else if (ob < 1440) { bsrc = Wpk; bstride = PD_DIM; bloc = ob - 1296; }
    else                { bsrc = nullptr; bstride = 0;  bloc = 0; }
    for (int k0 = 0; k0 < C_DIM; k0 += 32) {
      {
        const float* ap = single + (size_t)(n0 + srow) * C_DIM + k0 + skk;
        f32x4 a0 = *(const f32x4*)ap;
        f32x4 a1 = *(const f32x4*)(ap + 4);
        float xs[8] = {a0.x, a0.y, a0.z, a0.w, a1.x, a1.y, a1.z, a1.w};
        short8 hi, lo;
#pragma unroll
        for (int j = 0; j < 8; ++j) {
          unsigned short h = f2bf(xs[j]);
          hi[j] = (short)h;
          lo[j] = (short)f2bf(xs[j] - bf2f(h));
        }
        *(short8*)&Ah[srow * LDT + skk] = hi;
        *(short8*)&Al[srow * LDT + skk] = lo;
      }
      {
        float xs[8] = {0.f, 0.f, 0.f, 0.f, 0.f, 0.f, 0.f, 0.f};
        if (bsrc) {
          const float* bp = bsrc + (size_t)(k0 + kr) * bstride + bloc;
          f32x4 b0 = *(const f32x4*)bp;
          f32x4 b1 = *(const f32x4*)(bp + 4);
          xs[0] = b0.x; xs[1] = b0.y; xs[2] = b0.z; xs[3] = b0.w;
          xs[4] = b1.x; xs[5] = b1.y; xs[6] = b1.z; xs[7] = b1.w;
        }
#pragma unroll
        for (int j = 0; j < 8; ++j) {
          unsigned short h = f2bf(xs[j]);
          Bh[(og * 8 + j) * LDT + kr] = h;
          Bl[(og * 8 + j) * LDT + kr] = f2bf(xs[j] - bf2f(h));
        }
      }
      __syncthreads();
#pragma unroll
      for (int i = 0; i < 2; ++i) {
        const int ar = (wr * 32 + i * 16 + (lane & 15)) * LDT + (lane >> 4) * 8;
        short8 ah = *(short8*)&Ah[ar];
        short8 al = *(short8*)&Al[ar];
#pragma unroll
        for (int j = 0; j < 2; ++j) {
          const int br = (wc * 32 + j * 16 + (lane & 15)) * LDT + (lane >> 4) * 8;
          short8 bh = *(short8*)&Bh[br];
          short8 bl = *(short8*)&Bl[br];
          acc[i][j] = __builtin_amdgcn_mfma_f32_16x16x32_bf16(ah, bh, acc[i][j], 0, 0, 0);
          acc[i][j] = __builtin_amdgcn_mfma_f32_16x16x32_bf16(ah, bl, acc[i][j], 0, 0, 0);
          acc[i][j] = __builtin_amdgcn_mfma_f32_16x16x32_bf16(al, bh, acc[i][j], 0, 0, 0);
        }
      }
      __syncthreads();
    }
#pragma unroll
    for (int i = 0; i < 2; ++i)
#pragma unroll
      for (int j = 0; j < 2; ++j)
#pragma unroll
        for (int rr = 0; rr < 4; ++rr) {
          int r = n0 + wr * 32 + i * 16 + (lane >> 4) * 4 + rr;
          int c = o0 + wc * 32 + j * 16 + (lane & 15);
          proj[(size_t)r * NOP_DIM + c] = acc[i][j][rr];
        }
  } else if (blockIdx.x < NPROJ + NWOUT) {
    // ---------- WoutT transpose ----------
    float* T = (float*)SMEM;  // [64][68] padded
    const int b2 = blockIdx.x - NPROJ;
    const int k0 = (b2 % 6) * 64, o0 = (b2 / 6) * 64;
    const int r = t >> 2, cq = t & 3;
    {
      const float* srcrow = Wout + (size_t)(k0 + r) * C_DIM + o0 + cq * 16;
#pragma unroll
      for (int j = 0; j < 4; ++j) {
        f32x4 v = *(const f32x4*)(srcrow + j * 4);
        T[r * 68 + cq * 16 + j * 4 + 0] = v.x;
        T[r * 68 + cq * 16 + j * 4 + 1] = v.y;
        T[r * 68 + cq * 16 + j * 4 + 2] = v.z;
        T[r * 68 + cq * 16 + j * 4 + 3] = v.w;
      }
    }
    __syncthreads();
    {
      ushort4v w0, w1, w2, w3;
#pragma unroll
      for (int j = 0; j < 4; ++j) {
        w0[j] = f16bits(T[(cq * 16 + j) * 68 + r]);
        w1[j] = f16bits(T[(cq * 16 + 4 + j) * 68 + r]);
        w2[j] = f16bits(T[(cq * 16 + 8 + j) * 68 + r]);
        w3[j] = f16bits(T[(cq * 16 + 12 + j) * 68 + r]);
      }
      f16* dst = WoutT + (size_t)(o0 + r) * C_DIM + k0 + cq * 16;
      *(ushort4v*)(dst + 0)  = w0;
      *(ushort4v*)(dst + 4)  = w1;
      *(ushort4v*)(dst + 8)  = w2;
      *(ushort4v*)(dst + 12) = w3;
    }
  } else {
    // ---------- bias: contiguous global_load_lds stage -> swizzled read -> MFMA ----------
    const int w = t >> 6;
    const int r16 = lane & 15, g = lane >> 4;
    const size_t nm0 = (size_t)(blockIdx.x - NPROJ - NWOUT) * 64;
    short8 bfr[4];
#pragma unroll
    for (int kst = 0; kst < 4; ++kst)
#pragma unroll
      for (int j = 0; j < 8; ++j) {
        int k = kst * 32 + g * 8 + j;
        float v = (r16 < 12) ? Wpair[k * H_NUM + r16] : 0.f;
        bfr[kst][j] = (short)f2bf(v);
      }
    {
      const char* gbase = (const char*)(pair + nm0 * 128);
#pragma unroll
      for (int i = 0; i < 8; ++i) {
        unsigned B = (unsigned)((i * 4 + w) * 1024 + lane * 16);  // linear LDS byte
        unsigned src = B ^ (((B >> 9) & 7u) << 4);                // swizzled global byte
#ifdef HAVE_GLL
        __builtin_amdgcn_global_load_lds(
            (const __attribute__((address_space(1))) unsigned*)(gbase + src),
            (__attribute__((address_space(3))) unsigned*)(SMEM + (i * 4 + w) * 1024),
            16, 0, 0);
#else
        *(f32x4*)(SMEM + B) = *(const f32x4*)(gbase + src);
#endif
      }
    }
    __syncthreads();
    f32x4 acc = {};
    const unsigned xr = (unsigned)((r16 & 7) << 4);
#pragma unroll
    for (int kst = 0; kst < 4; ++kst) {
      unsigned L = (unsigned)((w * 16 + r16) * 512 + kst * 128 + g * 32);
      f32x4 v0 = *(const f32x4*)(SMEM + (L ^ xr));
      f32x4 v1 = *(const f32x4*)(SMEM + ((L + 16) ^ xr));
      u32x4 pk;
      pk.x = packbf(v0.x, v0.y);
      pk.y = packbf(v0.z, v0.w);
      pk.z = packbf(v1.x, v1.y);
      pk.w = packbf(v1.z, v1.w);
      acc = __builtin_amdgcn_mfma_f32_16x16x32_bf16(__builtin_bit_cast(short8, pk),
                                                    bfr[kst], acc, 0, 0, 0);
    }
    if (r16 < 12) {
      ushort4v pkk;
#pragma unroll
      for (int rr = 0; rr < 4; ++rr) pkk[rr] = f16bits(acc[rr]);
      *(ushort4v*)(bias + (((size_t)r16 << 20) + nm0 + w * 16 + g * 4)) = pkk;
    }
  }
}

// ============ k_assemble ============
__global__ __launch_bounds__(256) void k_assemble(
    const float* __restrict__ proj, const float* __restrict__ rot,
    const float* __restrict__ bq, const float* __restrict__ bk,
    const float* __restrict__ bv, const float* __restrict__ bpq,
    const float* __restrict__ bpk,
    f16* __restrict__ Qtf, f16* __restrict__ Ktf, f16* __restrict__ Vt) {
  const int n0 = blockIdx.x * 4, t = threadIdx.x;
  __shared__ float qv[4][384], kv[4][384], qgv[4][144], kgv[4][144], skv[4][12];
  __shared__ f16 vbuf[384][4];
#pragma unroll
  for (int ln = 0; ln < 4; ++ln) {
    const float* pr = proj + (size_t)(n0 + ln) * NOP_DIM;
    const float* R = rot + (n0 + ln) * 9;
    for (int c = t; c < 384; c += 256) {
      qv[ln][c] = pr[c] + bq[c];
      kv[ln][c] = pr[384 + c] + bk[c];
      vbuf[c][ln] = (f16)(pr[768 + c] + bv[c]);
    }
    for (int s = t; s < 144; s += 256) {
      int h = s / 12, pj = s - h * 12, p = pj / 3, j = pj - p * 3;
      float qg = 0.f, kg = 0.f;
      for (int i = 0; i < 3; ++i) {
        qg += (pr[1152 + h * 12 + p * 3 + i] + bpq[h * 12 + p * 3 + i]) * R[i * 3 + j];
        kg += (pr[1296 + h * 12 + p * 3 + i] + bpk[h * 12 + p * 3 + i]) * R[i * 3 + j];
      }
      qgv[ln][s] = qg;
      kgv[ln][s] = kg;
    }
  }
  __syncthreads();
  if (t < 48) {
    int ln = t / 12, h = t - ln * 12;
    float sk = 0.f;
    for (int pj = 0; pj < 12; ++pj) sk += kgv[ln][h * 12 + pj] * kgv[ln][h * 12 + pj];
    skv[ln][h] = -0.5f * SCALE_F * sk;
  }
  __syncthreads();
  for (int idx = t; idx < 4 * 12 * KD; idx += 256) {
    int ln = idx / 1152, rem = idx - ln * 1152;
    int h = rem / KD, s = rem - h * KD;
    float qo = 0.f, ko = 0.f;
    if (s < 32) {
      qo = SCALE_F * qv[ln][h * 32 + s];
      ko = kv[ln][h * 32 + s];
    } else if (s < 44) {
      int j = s - 32;
      qo = f16hi(SCALE_F * qgv[ln][h * 12 + j]);
      ko = f16hi(kgv[ln][h * 12 + j]);
    } else if (s < 56) {
      int j = s - 44;
      qo = f16hi(SCALE_F * qgv[ln][h * 12 + j]);
      ko = kgv[ln][h * 12 + j] - f16hi(kgv[ln][h * 12 + j]);
    } else if (s < 68) {
      int j = s - 56;
      float sq = SCALE_F * qgv[ln][h * 12 + j];
      qo = sq - f16hi(sq);
      ko = f16hi(kgv[ln][h * 12 + j]);
    } else if (s == 68) {
      qo = 1.f;
      ko = f16hi(skv[ln][h]);
    } else if (s == 69) {
      qo = 1.f;
      ko = skv[ln][h] - f16hi(skv[ln][h]);
    }
    Qtf[((size_t)h * N_TOK + n0 + ln) * KD + s] = (f16)qo;
    Ktf[((size_t)h * N_TOK + n0 + ln) * KD + s] = (f16)ko;
  }
  __syncthreads();
  for (int r = t; r < 384; r += 256)
    *(ushort4v*)(Vt + ((size_t)r << 10) + n0) = *(ushort4v*)&vbuf[r][0];
}

// ============ k_attn2: flash attention; Kt/Vt direct-from-L2, bias dbuf LDS ============
__global__ __launch_bounds__(256, 4) void k_attn2(const f16* __restrict__ Qtf,
                                                  const f16* __restrict__ Ktf,
                                                  const f16* __restrict__ Vt,
                                                  const f16* __restrict__ bias,
                                                  float* __restrict__ psum) {
  __shared__ unsigned short biasS[2][64 * 72];
  __shared__ unsigned short PS[4][16 * 72];
  const int h = blockIdx.x, nt = blockIdx.y, ms = blockIdx.z;
  const int t = threadIdx.x, lane = t & 63, w = t >> 6;
  const int r16 = lane & 15, g = lane >> 4;
  const int n0 = nt * 64, mbase = ms * 256;

  half8 qf[3];
  {
    const f16* Qrow = Qtf + ((size_t)h * N_TOK + n0 + w * 16 + r16) * KD;
#pragma unroll
    for (int kst = 0; kst < 3; ++kst)
      qf[kst] = __builtin_bit_cast(half8, *(const u32x4*)(Qrow + kst * 32 + g * 8));
  }
  f32x4 accv[2] = {};
  float Mh[4] = {-3e38f, -3e38f, -3e38f, -3e38f};
  float Sh[4] = {0.f, 0.f, 0.f, 0.f};

  // prologue: stage bias chunk 0
  {
    const int rb = t >> 2;
    const f16* src = bias + ((size_t)h << 20) + (size_t)(n0 + rb) * N_TOK + mbase + (t & 3) * 16;
#pragma unroll
    for (int i = 0; i < 2; ++i)
      *(u32x4*)&biasS[0][rb * 72 + (t & 3) * 16 + i * 8] = *(const u32x4*)(src + i * 8);
  }
  __syncthreads();

  for (int sc = 0; sc < 4; ++sc) {
    const int m0 = mbase + sc * 64;
    const int cur = sc & 1;
    // stage next bias chunk into the other buffer (safe: prev readers synced)
    if (sc < 3) {
      const int rb = t >> 2;
      const f16* src = bias + ((size_t)h << 20) + (size_t)(n0 + rb) * N_TOK + (m0 + 64) + (t & 3) * 16;
#pragma unroll
      for (int i = 0; i < 2; ++i)
        *(u32x4*)&biasS[cur ^ 1][rb * 72 + (t & 3) * 16 + i * 8] = *(const u32x4*)(src + i * 8);
    }

    // QK^T: B-fragments straight from global (L2-hot), exactly fragment-shaped 16B loads
    f32x4 sacc[4] = {};
#pragma unroll
    for (int mt = 0; mt < 4; ++mt) {
      const f16* Krow = Ktf + ((size_t)h * N_TOK + m0 + mt * 16 + r16) * KD;
#pragma unroll
      for (int kst = 0; kst < 3; ++kst) {
        half8 b = __builtin_bit_cast(half8, *(const u32x4*)(Krow + kst * 32 + g * 8));
        sacc[mt] = __builtin_amdgcn_mfma_f32_16x16x32_f16(qf[kst], b, sacc[mt], 0, 0, 0);
      }
    }
#pragma unroll
    for (int mt = 0; mt < 4; ++mt)
#pragma unroll
      for (int rr = 0; rr < 4; ++rr)
        sacc[mt][rr] += f16f(biasS[cur][(w * 16 + g * 4 + rr) * 72 + mt * 16 + r16]);

    float e[4], Mn[4];
#pragma unroll
    for (int rr = 0; rr < 4; ++rr) {
      float mx = fmaxf(fmaxf(sacc[0][rr], sacc[1][rr]), fmaxf(sacc[2][rr], sacc[3][rr]));
#pragma unroll
      for (int msk = 1; msk < 16; msk <<= 1) mx = fmaxf(mx, __shfl_xor(mx, msk));
      Mn[rr] = fmaxf(Mh[rr], mx);
      e[rr] = __expf(Mh[rr] - Mn[rr]);
      Mh[rr] = Mn[rr];
    }
    float rs[4] = {0.f, 0.f, 0.f, 0.f};
#pragma unroll
    for (int mt = 0; mt < 4; ++mt)
#pragma unroll
      for (int rr = 0; rr < 4; ++rr) {
        float p = __expf(sacc[mt][rr] - Mn[rr]);
        rs[rr] += p;
        PS[w][(g * 4 + rr) * 72 + mt * 16 + r16] = f16bits(p);
      }
#pragma unroll
    for (int rr = 0; rr < 4; ++rr) {
#pragma unroll
      for (int msk = 1; msk < 16; msk <<= 1) rs[rr] += __shfl_xor(rs[rr], msk);
      Sh[rr] = Sh[rr] * e[rr] + rs[rr];
    }
#pragma unroll
    for (int vt = 0; vt < 2; ++vt)
#pragma unroll
      for (int rr = 0; rr < 4; ++rr) accv[vt][rr] *= e[rr];

    // PV: P from per-wave LDS (no barrier needed), V direct from global
#pragma unroll
    for (int kst2 = 0; kst2 < 2; ++kst2) {
      half8 pa = __builtin_bit_cast(half8, *(u32x4*)&PS[w][r16 * 72 + kst2 * 32 + g * 8]);
#pragma unroll
      for (int vt = 0; vt < 2; ++vt) {
        half8 bvv = __builtin_bit_cast(
            half8, *(const u32x4*)(Vt + (((size_t)(h * 32 + vt * 16 + r16)) << 10) + m0 + kst2 * 32 + g * 8));
        accv[vt] = __builtin_amdgcn_mfma_f32_16x16x32_f16(pa, bvv, accv[vt], 0, 0, 0);
      }
    }
    __syncthreads();  // bias[cur^1] staged AND everyone done with bias[cur]
  }

  float* ps = psum + (((size_t)h * 4 + ms) * N_TOK) * 36;
#pragma unroll
  for (int rr = 0; rr < 4; ++rr) {
    int n = n0 + w * 16 + g * 4 + rr;
    if (r16 == 0) {
      ps[(size_t)n * 36 + 0] = Mh[rr];
      ps[(size_t)n * 36 + 1] = Sh[rr];
    }
#pragma unroll
    for (int vt = 0; vt < 2; ++vt)
      ps[(size_t)n * 36 + 2 + vt * 16 + r16] = accv[vt][rr];
  }
}

// ============ k_epi: 4 tokens/block; merge + outproj + residual + LayerNorm ============
__global__ __launch_bounds__(384) void k_epi(const float* __restrict__ psum,
                                             const f16* __restrict__ WoutT,
                                             const float* __restrict__ bout,
                                             const float* __restrict__ single,
                                             const float* __restrict__ gamma,
                                             const float* __restrict__ beta,
                                             float* __restrict__ out) {
  const int nb = blockIdx.x * 4, t = threadIdx.x;
  __shared__ f16 ar4[4][384];
  __shared__ float red[4][6][2];
  const int h = t >> 5, vc = t & 31, w = t >> 6;
  const size_t sstr = (size_t)N_TOK * 36;
#pragma unroll
  for (int tk = 0; tk < 4; ++tk) {
    const float* pb = psum + ((size_t)(h * 4) * N_TOK + (nb + tk)) * 36;
    float M = -3e38f;
#pragma unroll
    for (int s = 0; s < 4; ++s) M = fmaxf(M, pb[s * sstr]);
    float den = 0.f, num = 0.f;
#pragma unroll
    for (int s = 0; s < 4; ++s) {
      float e = __expf(pb[s * sstr] - M);
      den += pb[s * sstr + 1] * e;
      num += pb[s * sstr + 2 + vc] * e;
    }
    ar4[tk][t] = (f16)(num / den);
  }
  __syncthreads();
  float d[4] = {0.f, 0.f, 0.f, 0.f};
  {
    const u32x4* wp = (const u32x4*)(WoutT + (size_t)t * C_DIM);
    for (int i = 0; i < 48; ++i) {
      u32x4 wv = wp[i];
      half2v w0 = __builtin_bit_cast(half2v, wv.x);
      half2v w1 = __builtin_bit_cast(half2v, wv.y);
      half2v w2 = __builtin_bit_cast(half2v, wv.z);
      half2v w3 = __builtin_bit_cast(half2v, wv.w);
#pragma unroll
      for (int tk = 0; tk < 4; ++tk) {
        u32x4 av = *(const u32x4*)&ar4[tk][i * 8];
        d[tk] = fdot2f(__builtin_bit_cast(half2v, av.x), w0, d[tk]);
        d[tk] = fdot2f(__builtin_bit_cast(half2v, av.y), w1, d[tk]);
        d[tk] = fdot2f(__builtin_bit_cast(half2v, av.z), w2, d[tk]);
        d[tk] = fdot2f(__builtin_bit_cast(half2v, av.w), w3, d[tk]);
      }
    }
  }
  const float bo_ = bout[t], ga = gamma[t], be = beta[t];
  float x[4];
#pragma unroll
  for (int tk = 0; tk < 4; ++tk) {
    x[tk] = d[tk] + bo_ + single[(size_t)(nb + tk) * C_DIM + t];
    float s1 = x[tk], q1 = x[tk] * x[tk];
#pragma unroll
    for (int m = 1; m < 64; m <<= 1) {
      s1 += __shfl_xor(s1, m);
      q1 += __shfl_xor(q1, m);
    }
    if ((t & 63) == 0) { red[tk][w][0] = s1; red[tk][w][1] = q1; }
  }
  __syncthreads();
#pragma unroll
  for (int tk = 0; tk < 4; ++tk) {
    float S = 0.f, Q = 0.f;
#pragma unroll
    for (int i = 0; i < 6; ++i) { S += red[tk][i][0]; Q += red[tk][i][1]; }
    const float mu = S * (1.f / 384.f);
    const float var = Q * (1.f / 384.f) - mu * mu;
    const float rs = rsqrtf(var + 1e-5f);
    out[(size_t)(nb + tk) * C_DIM + t] = (x[tk] - mu) * rs * ga + be;
  }
}

// ============ launcher ============
extern "C" void kernel_launch(void* const* d_in, const int* in_sizes, int n_in,
                              void* d_out, int out_size, void* d_ws, size_t ws_size,
                              hipStream_t stream) {
  const float* single = (const float*)d_in[0];
  const float* pair   = (const float*)d_in[1];
  const float* rot    = (const float*)d_in[2];
  const float* Wq = (const float*)d_in[4];   const float* bq = (const float*)d_in[5];
  const float* Wk = (const float*)d_in[6];   const float* bk = (const float*)d_in[7];
  const float* Wv = (const float*)d_in[8];   const float* bv = (const float*)d_in[9];
  const float* Wpair = (const float*)d_in[10];
  const float* Wpq = (const float*)d_in[12]; const float* bpq = (const float*)d_in[13];
  const float* Wpk = (const float*)d_in[14]; const float* bpk = (const float*)d_in[15];
  const float* Wout = (const float*)d_in[16]; const float* bout = (const float*)d_in[17];
  const float* gamma = (const float*)d_in[18]; const float* beta = (const float*)d_in[19];
  float* out = (float*)d_out;

  char* ws = (char*)d_ws;
  size_t off = 0;
  auto alloc = [&](size_t bytes) -> void* {
    void* p = ws + off;
    off += (bytes + 255) & ~(size_t)255;
    return p;
  };
  f16* Qtf = (f16*)alloc((size_t)12 * N_TOK * KD * 2);
  f16* Ktf = (f16*)alloc((size_t)12 * N_TOK * KD * 2);
  f16* Vt  = (f16*)alloc((size_t)C_DIM * N_TOK * 2);
  f16* WoutT = (f16*)alloc((size_t)C_DIM * C_DIM * 2);
  float* proj = (float*)alloc((size_t)N_TOK * NOP_DIM * 4);
  f16* bias = (f16*)alloc((size_t)12 * N_TOK * N_TOK * 2);
  float* psum = (float*)alloc((size_t)12 * 4 * N_TOK * 36 * 4);

  k_projbias<<<dim3(NPROJ + NWOUT + N_TOK * N_TOK / 64), dim3(256), 0, stream>>>(
      single, Wq, Wk, Wv, Wpq, Wpk, Wpair, Wout, proj, pair, WoutT, bias);
  k_assemble<<<dim3(N_TOK / 4), dim3(256), 0, stream>>>(proj, rot, bq, bk, bv, bpq, bpk, Qtf, Ktf, Vt);
  k_attn2<<<dim3(12, 16, 4), dim3(256), 0, stream>>>(Qtf, Ktf, Vt, bias, psum);
  k_epi<<<dim3(N_TOK / 4), dim3(384), 0, stream>>>(psum, WoutT, bout, single, gamma, beta, out);
}